// Round 6
// baseline (413.500 us; speedup 1.0000x reference)
//
#include <hip/hip_runtime.h>
#include <hip/hip_bf16.h>

typedef unsigned short u16;
typedef unsigned int   u32;
typedef short  s16x8 __attribute__((ext_vector_type(8)));
typedef __bf16 bf16x8 __attribute__((ext_vector_type(8)));
typedef float  f32x4 __attribute__((ext_vector_type(4)));

#define D_ 512
#define NR 33344          // B*L*M + B*72 = 32768 + 576
#define NRP 33792         // padded to 66*512 (block = 512 rows)
#define TROWS 32768       // temp rows
#define TOUT_OFF  0UL
#define OOUT_OFF  16809984UL
#define TATTN_OFF 17072128UL
#define OATTN_OFF 35946496UL

__device__ __forceinline__ float bf2f(u16 x) {
    union { u32 u; float f; } v; v.u = ((u32)x) << 16; return v.f;
}
__device__ __forceinline__ u16 f2bf(float f) {
    union { float f; u32 u; } v; v.f = f;
    u32 u = v.u;
    return (u16)((u + 0x7fffu + ((u >> 16) & 1u)) >> 16);
}
// load 8 contiguous fp32, round-to-nearest-even to bf16x8
__device__ __forceinline__ s16x8 cvt8(const float* p) {
    float4 a = *(const float4*)p;
    float4 b = *(const float4*)(p + 4);
    s16x8 r;
    r[0] = (short)f2bf(a.x); r[1] = (short)f2bf(a.y);
    r[2] = (short)f2bf(a.z); r[3] = (short)f2bf(a.w);
    r[4] = (short)f2bf(b.x); r[5] = (short)f2bf(b.y);
    r[6] = (short)f2bf(b.z); r[7] = (short)f2bf(b.w);
    return r;
}
__device__ __forceinline__ f32x4 mfma16(s16x8 a, s16x8 b, f32x4 c) {
    return __builtin_amdgcn_mfma_f32_16x16x32_bf16(
        __builtin_bit_cast(bf16x8, a), __builtin_bit_cast(bf16x8, b), c, 0, 0, 0);
}
__device__ __forceinline__ void gload_lds16(const u16* g, u16* l) {
    __builtin_amdgcn_global_load_lds(
        (const __attribute__((address_space(1))) void*)g,
        (__attribute__((address_space(3))) void*)l, 16, 0, 0);
}

// row r of the fused A matrix -> source row pointer (fp32)
__device__ __forceinline__ const float* a_src_row(int r, const float* temporal, const float* others) {
    if (r < TROWS) {
        int b = r >> 12;
        return temporal + (size_t)(r + 8 * (b + 1)) * D_;
    }
    int rr = r - TROWS;
    int b = rr / 72, j = rr - b * 72;
    return (j < 8) ? (temporal + (size_t)(b * 4104 + j) * D_)
                   : (others   + (size_t)(b * 64 + j - 8) * D_);
}

// ---------------- pre-pass: fp32 -> bf16 ----------------
// A stored K-STEP-MAJOR: element (row,k) at Ab[(row>>4)*8192 + ks*512 + q*128 + (row&15)*8 + e]
// with k = ks*32 + q*8 + e.  Threads iterate over the OUTPUT offset (idx*8 -> perfectly
// coalesced sequential 16B stores) and compute the matching fp32 source chunk (32B reads,
// sector-complete within a wave).
__global__ __launch_bounds__(256) void prep_4715(
    const float* __restrict__ temporal, const float* __restrict__ others,
    const float* __restrict__ Wq, const float* __restrict__ Wk, const float* __restrict__ Wv,
    u16* __restrict__ Ab, u16* __restrict__ Wb)
{
    int idx = blockIdx.x * 256 + threadIdx.x;   // one thread = 8 u16 out
    if (idx < NRP * 64) {
        // output-linear mapping
        int rb  = idx >> 10;            // 1024 chunks per 16-row block (8192 u16)
        int rem = idx & 1023;
        int ks  = rem >> 6;             // 64 chunks per k-step slab (512 u16)
        int qq  = (rem >> 4) & 3;       // 16 chunks per q slab (128 u16)
        int ri  = rem & 15;             // 1 chunk per row (8 u16)
        int r   = rb * 16 + ri;
        u16* dst = Ab + (size_t)idx * 8;
        if (r >= NR) {
            u32* d32 = (u32*)dst;
            d32[0] = 0; d32[1] = 0; d32[2] = 0; d32[3] = 0;
            return;
        }
        *(s16x8*)dst = cvt8(a_src_row(r, temporal, others) + ks * 32 + qq * 8);
    } else {
        int r  = idx >> 6;
        int ch = (idx & 63) * 8;
        if (r >= NRP + 1536) return;
        int n = r - NRP;
        const float* W = (n < 512) ? Wq : (n < 1024 ? Wk : Wv);
        *(s16x8*)(Wb + (size_t)n * D_ + ch) = cvt8(W + (size_t)(n & 511) * D_ + ch);
    }
}

// ---------------- QKV GEMM: resident 64-col B-panel, 2 blocks/CU, streaming A ----------------
// Block = 512 rows x 64 cols, 8 waves (wave owns 64 rows, acc[4][4]).  B-panel 64 KB staged
// once; pool 73.7 KB (B + padded-stride epilogue) -> 2 resident blocks/CU so one block's
// B-staging/epilogue overlaps the other's MFMA stream (the overlap a 1-block/CU schedule
// can't get at K=512).  A streamed dense from k-step-major layout with 1-step prefetch;
// zero barriers in the main loop.  Epilogue stride 72 u16 -> rotating bank base, no
// power-of-2 conflicts; coalesced 128B row stores.
__global__ __launch_bounds__(512, 4) void qkv_gemm2_4715(
    const u16* __restrict__ Ab, const u16* __restrict__ Wb,
    const float* __restrict__ bq, const float* __restrict__ bk, const float* __restrict__ bv,
    u16* __restrict__ Qb, u16* __restrict__ Kb, u16* __restrict__ Vb)
{
    __shared__ __align__(16) u16 pool[36864];     // 73.7 KB: B panel (32768), epilogue overlay
    const int tid  = threadIdx.x;
    const int lane = tid & 63;
    const int w    = tid >> 6;                    // 8 waves

    // bijective XCD swizzle: 1584 blocks = 8 * 198 exactly; nblk fastest within a chunk
    int orig = blockIdx.x;
    int gx = (orig & 7) * 198 + (orig >> 3);
    const int nblk = gx % 24;                     // 24 x 64-col panels share one A m-group
    const int mgrp = gx / 24;
    const int n0 = nblk * 64;

    // ---- stage B panel once: wave w loads rows w*8..w*8+7 (1 KB row each) ----
    // LDS[r][g] = global[r][(g&56) | ((g&7)^(r&7))]  (granule = 8 u16 = 16B)
    #pragma unroll
    for (int rr = 0; rr < 8; ++rr) {
        int r  = w * 8 + rr;
        int sg = (lane & 56) | ((lane & 7) ^ (r & 7));
        gload_lds16(Wb + (size_t)(n0 + r) * D_ + sg * 8, pool + r * 512);
    }
    asm volatile("s_waitcnt vmcnt(0)" ::: "memory");
    __builtin_amdgcn_sched_barrier(0);
    __syncthreads();

    const int fr = lane & 15;
    const int q  = lane >> 4;
    // this wave's 4 row-blocks (64 rows) in k-step-major layout; lane*8 = q*128 + fr*8
    const u16* pA = Ab + (size_t)(mgrp * 32 + w * 4) * 8192 + lane * 8;

    f32x4 acc[4][4];
    #pragma unroll
    for (int i = 0; i < 4; ++i)
        #pragma unroll
        for (int j = 0; j < 4; ++j) acc[i][j] = f32x4{0.f, 0.f, 0.f, 0.f};

    s16x8 aX[4], aY[4];

#define LOADA(buf, ks) {                                                   \
    _Pragma("unroll")                                                      \
    for (int mi = 0; mi < 4; ++mi)                                         \
        buf[mi] = *(const s16x8*)(pA + (size_t)mi * 8192 + (ks) * 512); }

#define KSTEP(cur, pre, ks) {                                              \
    if ((ks) + 1 < 16) LOADA(pre, (ks) + 1)                                \
    const int g = (ks) * 4 + q;                                            \
    const int pgo = ((g & 56) | ((g & 7) ^ (fr & 7))) * 8;                 \
    s16x8 bfr[4];                                                          \
    _Pragma("unroll")                                                      \
    for (int nj = 0; nj < 4; ++nj)                                         \
        bfr[nj] = *(const s16x8*)&pool[(nj * 16 + fr) * 512 + pgo];        \
    _Pragma("unroll")                                                      \
    for (int mi = 0; mi < 4; ++mi)                                         \
        _Pragma("unroll")                                                  \
        for (int nj = 0; nj < 4; ++nj)                                     \
            acc[mi][nj] = mfma16(cur[mi], bfr[nj], acc[mi][nj]); }

    LOADA(aX, 0)
    KSTEP(aX, aY, 0)  KSTEP(aY, aX, 1)  KSTEP(aX, aY, 2)  KSTEP(aY, aX, 3)
    KSTEP(aX, aY, 4)  KSTEP(aY, aX, 5)  KSTEP(aX, aY, 6)  KSTEP(aY, aX, 7)
    KSTEP(aX, aY, 8)  KSTEP(aY, aX, 9)  KSTEP(aX, aY, 10) KSTEP(aY, aX, 11)
    KSTEP(aX, aY, 12) KSTEP(aY, aX, 13) KSTEP(aX, aY, 14) KSTEP(aY, aX, 15)

#undef LOADA
#undef KSTEP

    // ---- epilogue: wave-private LDS staging (stride 72) -> coalesced 128B row stores ----
    __syncthreads();                              // all waves done reading the B panel
    u16* outp          = (nblk < 8) ? Qb : (nblk < 16 ? Kb : Vb);
    const float* biasp = (nblk < 8) ? bq : (nblk < 16 ? bk : bv);
    const int nn0 = (nblk & 7) * 64;
    const int c = lane & 15;
    u16* ep = pool + w * 4608;                    // wave-private [64][72] u16 = 9 KB

    float bias[4];
    #pragma unroll
    for (int nj = 0; nj < 4; ++nj) bias[nj] = biasp[nn0 + nj * 16 + c];

    #pragma unroll
    for (int mi = 0; mi < 4; ++mi)
        #pragma unroll
        for (int nj = 0; nj < 4; ++nj)
            #pragma unroll
            for (int p = 0; p < 4; ++p)
                ep[(mi * 16 + q * 4 + p) * 72 + nj * 16 + c] =
                    f2bf(acc[mi][nj][p] + bias[nj]);

    // read back: lane covers (row = rr*8 + lane>>3, granule = lane&7); 8 rows x 128B per instr
    #pragma unroll
    for (int rr = 0; rr < 8; ++rr) {
        int row = rr * 8 + (lane >> 3);
        s16x8 v = *(const s16x8*)&ep[row * 72 + (lane & 7) * 8];
        int grow = mgrp * 512 + w * 64 + row;
        if (grow < NR)
            *(s16x8*)&outp[(size_t)grow * D_ + nn0 + (lane & 7) * 8] = v;
    }
}

// ---------------- fallback fused QKV GEMM (fp32 in, cvt in staging) ----------------
__global__ __launch_bounds__(256) void qkv_gemm_4715(
    const float* __restrict__ temporal, const float* __restrict__ others,
    const float* __restrict__ Wq, const float* __restrict__ bq,
    const float* __restrict__ Wk, const float* __restrict__ bk,
    const float* __restrict__ Wv, const float* __restrict__ bv,
    u16* __restrict__ Qb, u16* __restrict__ Kb, u16* __restrict__ Vb)
{
    __shared__ __align__(16) u16 As[128][72];
    __shared__ __align__(16) u16 Bs[128][72];
    const int tid  = threadIdx.x;
    const int lane = tid & 63;
    const int wave = tid >> 6;
    const int wr = wave >> 1, wc = wave & 1;
    const int m0 = blockIdx.x * 128;
    const int n0 = blockIdx.y * 128;

    const float* arow[4];
    #pragma unroll
    for (int i = 0; i < 4; ++i) {
        int r = m0 + (tid >> 3) + i * 32;
        if (r >= NR) r = 0;
        arow[i] = a_src_row(r, temporal, others);
    }
    const float* brow[4];
    #pragma unroll
    for (int i = 0; i < 4; ++i) {
        int n = n0 + (tid >> 3) + i * 32;
        const float* W = (n < 512) ? Wq : (n < 1024 ? Wk : Wv);
        brow[i] = W + (size_t)(n & 511) * D_;
    }
    const int acol = (tid & 7) * 8;
    const int srow = tid >> 3;

    f32x4 acc[4][4];
    #pragma unroll
    for (int i = 0; i < 4; ++i)
        #pragma unroll
        for (int j = 0; j < 4; ++j) acc[i][j] = f32x4{0.f, 0.f, 0.f, 0.f};

    for (int k0 = 0; k0 < 512; k0 += 64) {
        #pragma unroll
        for (int i = 0; i < 4; ++i) {
            *(s16x8*)&As[srow + i * 32][acol] = cvt8(arow[i] + k0 + acol);
            *(s16x8*)&Bs[srow + i * 32][acol] = cvt8(brow[i] + k0 + acol);
        }
        __syncthreads();
        #pragma unroll
        for (int kk = 0; kk < 64; kk += 32) {
            const int kc = kk + (lane >> 4) * 8;
            const int fr = lane & 15;
            s16x8 af[4], bfr[4];
            #pragma unroll
            for (int i = 0; i < 4; ++i) af[i]  = *(const s16x8*)&As[wr * 64 + i * 16 + fr][kc];
            #pragma unroll
            for (int j = 0; j < 4; ++j) bfr[j] = *(const s16x8*)&Bs[wc * 64 + j * 16 + fr][kc];
            #pragma unroll
            for (int i = 0; i < 4; ++i)
                #pragma unroll
                for (int j = 0; j < 4; ++j)
                    acc[i][j] = mfma16(af[i], bfr[j], acc[i][j]);
        }
        __syncthreads();
    }
    const int q = lane >> 4, c = lane & 15;
    #pragma unroll
    for (int j = 0; j < 4; ++j) {
        int n = n0 + wc * 64 + j * 16 + c;
        u16* outp          = (n < 512) ? Qb : (n < 1024 ? Kb : Vb);
        const float* biasp = (n < 512) ? bq : (n < 1024 ? bk : bv);
        int nn = n & 511;
        float bias = biasp[nn];
        #pragma unroll
        for (int i = 0; i < 4; ++i) {
            int rb = m0 + wr * 64 + i * 16 + q * 4;
            #pragma unroll
            for (int p = 0; p < 4; ++p) {
                int r = rb + p;
                if (r < NR) outp[(size_t)r * D_ + nn] = f2bf(acc[i][j][p] + bias);
            }
        }
    }
}

// ---------------- temporal attention (MFMA, M padded 8->16, N padded 72->80/96) ----------------
__global__ __launch_bounds__(256) void temporal_attn_4715(
    const u16* __restrict__ Qb, const u16* __restrict__ Kb, const u16* __restrict__ Vb,
    float* __restrict__ out)
{
    const int blk = blockIdx.x;           // ((b*4 + hp)*32 + lc)
    const int lc = blk & 31;
    const int hp = (blk >> 5) & 3;
    const int b  = blk >> 7;
    const int tid = threadIdx.x, lane = tid & 63, w = tid >> 6;
    const int q = lane >> 4, c = lane & 15;

    __shared__ __align__(16) u16 KtsS[2][64][72];   // cross-wave, written once
    __shared__ __align__(16) u16 VtsS[2][64][96];   // cross-wave, written once
    __shared__ __align__(16) u16 KttW[4][8][72];    // wave-private
    __shared__ __align__(16) u16 VttW[4][64][8];    // wave-private
    __shared__ __align__(16) u16 Pw[4][16][104];    // wave-private (pad cols written once)

    const size_t srowbase = (size_t)TROWS + (size_t)b * 72 + 8;
    for (int cch = tid; cch < 1024; cch += 256) {
        int hh = cch >> 9;
        int o  = (cch >> 3) & 63;
        int d8 = (cch & 7) * 8;
        int hbase = (hp * 2 + hh) * 64;
        *(s16x8*)&KtsS[hh][o][d8] = *(const s16x8*)&Kb[(srowbase + o) * D_ + hbase + d8];
        s16x8 vv = *(const s16x8*)&Vb[(srowbase + o) * D_ + hbase + d8];
        #pragma unroll
        for (int jj = 0; jj < 8; ++jj) VtsS[hh][d8 + jj][8 + o] = (u16)vv[jj];
    }
    for (int z = tid; z < 2 * 64 * 24; z += 256) {
        int hh = z / (64 * 24); int rem = z - hh * 64 * 24;
        VtsS[hh][rem / 24][72 + rem % 24] = 0;
    }
    for (int z = tid; z < 4 * 16 * 24; z += 256) {
        int ww = z / (16 * 24); int rem = z - ww * 16 * 24;
        Pw[ww][rem / 24][80 + rem % 24] = 0;
    }
    __syncthreads();    // the ONLY barrier: everything below is wave-private

    const float scale = 0.125f;
    for (int ti = 0; ti < 8; ++ti) {
        const int tsk = w + 4 * ti;               // 0..31
        const int hh = tsk >> 4;
        const int il = tsk & 15;
        const int l  = lc * 16 + il;
        const int h  = hp * 2 + hh;
        const int hbase = h * 64;
        const size_t rbase = ((size_t)b * 512 + l) * 8;

        { // stage Ktt (8x64) for this wave
            int m = lane >> 3, d8 = (lane & 7) * 8;
            *(s16x8*)&KttW[w][m][d8] = *(const s16x8*)&Kb[(rbase + m) * D_ + hbase + d8];
        }
        { // stage Vtt^T (64 x 8)
            #pragma unroll
            for (int m = 0; m < 8; ++m)
                VttW[w][lane][m] = Vb[(rbase + m) * D_ + hbase + lane];
        }
        const int mq = (c < 8) ? c : (c - 8);
        s16x8 aq0 = *(const s16x8*)&Qb[(rbase + mq) * D_ + hbase + q * 8];
        s16x8 aq1 = *(const s16x8*)&Qb[(rbase + mq) * D_ + hbase + 32 + q * 8];
        asm volatile("s_waitcnt lgkmcnt(0)" ::: "memory");  // in-wave RAW on KttW/VttW

        // QK^T: 5 n-tiles of 16, k = 64 (2 steps)
        f32x4 sacc[5];
        #pragma unroll
        for (int j = 0; j < 5; ++j) sacc[j] = f32x4{0.f, 0.f, 0.f, 0.f};
        #pragma unroll
        for (int j = 0; j < 5; ++j) {
            int g = j * 16 + c;
            const u16* kp0;
            if (g < 8) kp0 = &KttW[w][g][0];
            else { int o = g - 8; if (o > 63) o = 63; kp0 = &KtsS[hh][o][0]; }
            s16x8 b0 = *(const s16x8*)(kp0 + q * 8);
            s16x8 b1 = *(const s16x8*)(kp0 + 32 + q * 8);
            sacc[j] = mfma16(aq0, b0, sacc[j]);
            sacc[j] = mfma16(aq1, b1, sacc[j]);
        }
        float ev[5][4];
        float mx[4] = {-1e30f, -1e30f, -1e30f, -1e30f};
        #pragma unroll
        for (int j = 0; j < 5; ++j) {
            bool valid = (j < 4) || (c < 8);
            #pragma unroll
            for (int p = 0; p < 4; ++p) {
                float v = sacc[j][p] * scale;
                ev[j][p] = valid ? v : -1e30f;
                if (valid) mx[p] = fmaxf(mx[p], v);
            }
        }
        #pragma unroll
        for (int msk = 1; msk < 16; msk <<= 1)
            #pragma unroll
            for (int p = 0; p < 4; ++p)
                mx[p] = fmaxf(mx[p], __shfl_xor(mx[p], msk, 16));
        float sm[4] = {0.f, 0.f, 0.f, 0.f};
        #pragma unroll
        for (int j = 0; j < 5; ++j) {
            bool valid = (j < 4) || (c < 8);
            #pragma unroll
            for (int p = 0; p < 4; ++p) {
                float e = valid ? __expf(ev[j][p] - mx[p]) : 0.f;
                ev[j][p] = e;
                sm[p] += e;
            }
        }
        #pragma unroll
        for (int msk = 1; msk < 16; msk <<= 1)
            #pragma unroll
            for (int p = 0; p < 4; ++p)
                sm[p] += __shfl_xor(sm[p], msk, 16);
        float inv[4];
        #pragma unroll
        for (int p = 0; p < 4; ++p) inv[p] = 1.0f / sm[p];

        float* attnp = out + TATTN_OFF + ((((size_t)b * 8 + h) * 512 + l) * 8) * 72;
        #pragma unroll
        for (int j = 0; j < 5; ++j) {
            #pragma unroll
            for (int p = 0; p < 4; ++p) {
                int row = q * 4 + p;
                int col = j * 16 + c;
                float pv = ev[j][p] * inv[p];
                Pw[w][row][col] = f2bf(pv);
                if (row < 8 && col < 72)
                    attnp[(size_t)row * 72 + col] = pv;
            }
        }
        asm volatile("s_waitcnt lgkmcnt(0)" ::: "memory");  // in-wave RAW on Pw

        f32x4 oacc[4];
        #pragma unroll
        for (int j = 0; j < 4; ++j) oacc[j] = f32x4{0.f, 0.f, 0.f, 0.f};
        #pragma unroll
        for (int ks = 0; ks < 3; ++ks) {
            s16x8 ap = *(const s16x8*)&Pw[w][c][ks * 32 + q * 8];
            #pragma unroll
            for (int j = 0; j < 4; ++j) {
                int d = j * 16 + c;
                int kb = ks * 32 + q * 8;
                const u16* vp = (kb == 0) ? &VttW[w][d][0] : &VtsS[hh][d][kb];
                s16x8 bp = *(const s16x8*)vp;
                oacc[j] = mfma16(ap, bp, oacc[j]);
            }
        }
        float* toutp = out + (((size_t)b * 513 + l + 1) * 8) * 512 + hbase;
        #pragma unroll
        for (int j = 0; j < 4; ++j) {
            int d = j * 16 + c;
            #pragma unroll
            for (int p = 0; p < 4; ++p) {
                int row = q * 4 + p;
                if (row < 8)
                    toutp[(size_t)row * 512 + d] = oacc[j][p];
            }
        }
    }
}

// ---------------- others (ss) attention ----------------
__global__ __launch_bounds__(256) void others_attn_4715(
    const u16* __restrict__ Qb, const u16* __restrict__ Kb, const u16* __restrict__ Vb,
    float* __restrict__ out)
{
    const int blk = blockIdx.x;       // ((b*8 + h)*4 + mq)
    const int mq = blk & 3;
    const int h  = (blk >> 2) & 7;
    const int b  = blk >> 5;
    const int tid = threadIdx.x;
    const int hbase = h * 64;
    const size_t rbase = (size_t)TROWS + (size_t)b * 72;

    __shared__ float Qo[18][68];
    __shared__ float Ko[72][68];
    __shared__ float VoT[64][84];
    __shared__ float S[18][80];

    for (int e = tid; e < 72 * 64; e += 256) {
        int r = e >> 6, d = e & 63;
        Ko[r][d]  = bf2f(Kb[(rbase + r) * D_ + hbase + d]);
        VoT[d][r] = bf2f(Vb[(rbase + r) * D_ + hbase + d]);
    }
    for (int e = tid; e < 18 * 64; e += 256) {
        int r = e >> 6, d = e & 63;
        Qo[r][d] = bf2f(Qb[(rbase + mq * 18 + r) * D_ + hbase + d]);
    }
    for (int e = tid; e < 64 * 12; e += 256) VoT[e / 12][72 + e % 12] = 0.f;
    __syncthreads();

    for (int e = tid; e < 18 * 72; e += 256) {
        int m = e / 72, n = e - m * 72;
        const float* qp = Qo[m];
        const float* kp = Ko[n];
        float s = 0.f;
        #pragma unroll
        for (int d = 0; d < 64; ++d) s += qp[d] * kp[d];
        S[m][n] = s * 0.125f;
    }
    __syncthreads();
    if (tid < 18) {
        int m = tid;
        float mx = -1e30f;
        for (int n = 0; n < 72; ++n) mx = fmaxf(mx, S[m][n]);
        float sm = 0.f;
        for (int n = 0; n < 72; ++n) { float e = __expf(S[m][n] - mx); S[m][n] = e; sm += e; }
        float inv = 1.f / sm;
        size_t arow = OATTN_OFF + (((size_t)b * 8 + h) * 72 + (mq * 18 + m)) * 72;
        for (int n = 0; n < 72; ++n) {
            float p = S[m][n] * inv; S[m][n] = p;
            out[arow + n] = p;
        }
    }
    __syncthreads();
    // others_ = others.reshape(B,-1,D), no transpose: (h,n,d) -> i=h*9+n/8, j=(n%8)*64+d
    for (int e = tid; e < 18 * 64; e += 256) {
        int m = e >> 6, d = e & 63;
        float o = 0.f;
        #pragma unroll
        for (int n = 0; n < 72; ++n) o += S[m][n] * VoT[d][n];
        int nq = mq * 18 + m;
        int i  = h * 9 + (nq >> 3);
        int jj = (nq & 7) * 64 + d;
        size_t oaddr;
        if (i < 8) oaddr = ((size_t)b * 513 * 8 + i) * 512 + jj;
        else       oaddr = OOUT_OFF + ((size_t)b * 64 + (i - 8)) * 512 + jj;
        out[oaddr] = o;
    }
}

extern "C" void kernel_launch(void* const* d_in, const int* in_sizes, int n_in,
                              void* d_out, int out_size, void* d_ws, size_t ws_size,
                              hipStream_t stream) {
    const float* temporal = (const float*)d_in[0];
    const float* others   = (const float*)d_in[1];
    const float* Wq = (const float*)d_in[2];
    const float* bq = (const float*)d_in[3];
    const float* Wk = (const float*)d_in[4];
    const float* bk = (const float*)d_in[5];
    const float* Wv = (const float*)d_in[6];
    const float* bv = (const float*)d_in[7];
    float* outp = (float*)d_out;
    u16* Qb = (u16*)d_ws;
    u16* Kb = Qb + (size_t)NR * D_;
    u16* Vb = Kb + (size_t)NR * D_;
    u16* Ab = Vb + (size_t)NR * D_;
    u16* Wb = Ab + (size_t)NRP * D_;
    const size_t need = ((size_t)3 * NR * D_ + (size_t)NRP * D_ + (size_t)1536 * D_) * 2;

    if (ws_size >= need) {
        hipLaunchKernelGGL(prep_4715, dim3((NRP + 1536) * 64 / 256), dim3(256), 0, stream,
                           temporal, others, Wq, Wk, Wv, Ab, Wb);
        hipLaunchKernelGGL(qkv_gemm2_4715, dim3(66 * 24), dim3(512), 0, stream,
                           Ab, Wb, bq, bk, bv, Qb, Kb, Vb);
    } else {
        hipLaunchKernelGGL(qkv_gemm_4715, dim3(261, 12), dim3(256), 0, stream,
                           temporal, others, Wq, bq, Wk, bk, Wv, bv, Qb, Kb, Vb);
    }
    hipLaunchKernelGGL(temporal_attn_4715, dim3(1024), dim3(256), 0, stream, Qb, Kb, Vb, outp);
    hipLaunchKernelGGL(others_attn_4715, dim3(256), dim3(256), 0, stream, Qb, Kb, Vb, outp);
}

// Round 7
// 350.942 us; speedup vs baseline: 1.1783x; 1.1783x over previous
//
#include <hip/hip_runtime.h>
#include <hip/hip_bf16.h>

typedef unsigned short u16;
typedef unsigned int   u32;
typedef short  s16x8 __attribute__((ext_vector_type(8)));
typedef __bf16 bf16x8 __attribute__((ext_vector_type(8)));
typedef float  f32x4 __attribute__((ext_vector_type(4)));

#define D_ 512
#define NR 33344          // B*L*M + B*72 = 32768 + 576
#define NRP 33792         // padded to 66*512 (block = 512 rows)
#define TROWS 32768       // temp rows
#define TOUT_OFF  0UL
#define OOUT_OFF  16809984UL
#define TATTN_OFF 17072128UL
#define OATTN_OFF 35946496UL

__device__ __forceinline__ float bf2f(u16 x) {
    union { u32 u; float f; } v; v.u = ((u32)x) << 16; return v.f;
}
__device__ __forceinline__ u16 f2bf(float f) {
    union { float f; u32 u; } v; v.f = f;
    u32 u = v.u;
    return (u16)((u + 0x7fffu + ((u >> 16) & 1u)) >> 16);
}
// load 8 contiguous fp32, round-to-nearest-even to bf16x8
__device__ __forceinline__ s16x8 cvt8(const float* p) {
    float4 a = *(const float4*)p;
    float4 b = *(const float4*)(p + 4);
    s16x8 r;
    r[0] = (short)f2bf(a.x); r[1] = (short)f2bf(a.y);
    r[2] = (short)f2bf(a.z); r[3] = (short)f2bf(a.w);
    r[4] = (short)f2bf(b.x); r[5] = (short)f2bf(b.y);
    r[6] = (short)f2bf(b.z); r[7] = (short)f2bf(b.w);
    return r;
}
__device__ __forceinline__ f32x4 mfma16(s16x8 a, s16x8 b, f32x4 c) {
    return __builtin_amdgcn_mfma_f32_16x16x32_bf16(
        __builtin_bit_cast(bf16x8, a), __builtin_bit_cast(bf16x8, b), c, 0, 0, 0);
}
__device__ __forceinline__ void gload_lds16(const u16* g, u16* l) {
    __builtin_amdgcn_global_load_lds(
        (const __attribute__((address_space(1))) void*)g,
        (__attribute__((address_space(3))) void*)l, 16, 0, 0);
}

// row r of the fused A matrix -> source row pointer (fp32)
__device__ __forceinline__ const float* a_src_row(int r, const float* temporal, const float* others) {
    if (r < TROWS) {
        int b = r >> 12;
        return temporal + (size_t)(r + 8 * (b + 1)) * D_;
    }
    int rr = r - TROWS;
    int b = rr / 72, j = rr - b * 72;
    return (j < 8) ? (temporal + (size_t)(b * 4104 + j) * D_)
                   : (others   + (size_t)(b * 64 + j - 8) * D_);
}

// ---------------- pre-pass: fp32 -> bf16 ----------------
// A stored K-STEP-MAJOR: element (row,k) at Ab[(row>>4)*8192 + ks*512 + q*128 + (row&15)*8 + e]
// with k = ks*32 + q*8 + e.  Threads iterate over the OUTPUT offset (idx*8 -> perfectly
// coalesced sequential 16B stores) and compute the matching fp32 source chunk (32B reads,
// sector-complete within a wave).
__global__ __launch_bounds__(256) void prep_4715(
    const float* __restrict__ temporal, const float* __restrict__ others,
    const float* __restrict__ Wq, const float* __restrict__ Wk, const float* __restrict__ Wv,
    u16* __restrict__ Ab, u16* __restrict__ Wb)
{
    int idx = blockIdx.x * 256 + threadIdx.x;   // one thread = 8 u16 out
    if (idx < NRP * 64) {
        // output-linear mapping
        int rb  = idx >> 10;            // 1024 chunks per 16-row block (8192 u16)
        int rem = idx & 1023;
        int ks  = rem >> 6;             // 64 chunks per k-step slab (512 u16)
        int qq  = (rem >> 4) & 3;       // 16 chunks per q slab (128 u16)
        int ri  = rem & 15;             // 1 chunk per row (8 u16)
        int r   = rb * 16 + ri;
        u16* dst = Ab + (size_t)idx * 8;
        if (r >= NR) {
            u32* d32 = (u32*)dst;
            d32[0] = 0; d32[1] = 0; d32[2] = 0; d32[3] = 0;
            return;
        }
        *(s16x8*)dst = cvt8(a_src_row(r, temporal, others) + ks * 32 + qq * 8);
    } else {
        int r  = idx >> 6;
        int ch = (idx & 63) * 8;
        if (r >= NRP + 1536) return;
        int n = r - NRP;
        const float* W = (n < 512) ? Wq : (n < 1024 ? Wk : Wv);
        *(s16x8*)(Wb + (size_t)n * D_ + ch) = cvt8(W + (size_t)(n & 511) * D_ + ch);
    }
}

// ---------------- QKV GEMM: resident-B-panel, streaming-A, 16 waves (round-5 structure) ----
// B-panel (128 cols x K512 = 128 KB) resident in LDS for the whole block; 16 waves
// (4/SIMD for latency hiding), each owns 32 A-rows streamed from the k-step-major
// Ab layout as dense contiguous 1 KB loads with an explicit 2-buffer 1-step prefetch.
// Zero barriers in the main loop. Epilogue stages output through the dead B-LDS with
// an XOR granule swizzle for coalesced 256B stores (measured: FETCH 44 MB, WRITE 100 MB,
// dur < 93 us -- best structure so far; round 6's 64-col/2-block variant thrashed L2).
__global__ __launch_bounds__(1024, 4) void qkv_gemm2_4715(
    const u16* __restrict__ Ab, const u16* __restrict__ Wb,
    const float* __restrict__ bq, const float* __restrict__ bk, const float* __restrict__ bv,
    u16* __restrict__ Qb, u16* __restrict__ Kb, u16* __restrict__ Vb)
{
    __shared__ __align__(16) u16 pool[65536];     // 128 KB: B panel, then epilogue buffer
    const int tid  = threadIdx.x;
    const int lane = tid & 63;
    const int w    = tid >> 6;                    // 16 waves, each owns 32 rows

    // XCD swizzle: 792 blocks = 8 * 99 exactly -> bijective chunking; nblk fastest
    int orig = blockIdx.x;
    int gx = (orig & 7) * 99 + (orig >> 3);
    const int nblk = gx % 12;
    const int mgrp = gx / 12;
    const int n0 = nblk * 128;

    // ---- stage B panel once: wave w loads rows w*8..w*8+7 (1 KB row each) ----
    // LDS[r][g] = global[r][(g&56) | ((g&7)^(r&7))]  (granule = 8 u16 = 16B)
    #pragma unroll
    for (int rr = 0; rr < 8; ++rr) {
        int r  = w * 8 + rr;
        int sg = (lane & 56) | ((lane & 7) ^ (r & 7));
        gload_lds16(Wb + (size_t)(n0 + r) * D_ + sg * 8, pool + r * 512);
    }
    asm volatile("s_waitcnt vmcnt(0)" ::: "memory");
    __builtin_amdgcn_sched_barrier(0);
    __syncthreads();

    const int fr = lane & 15;
    const int q  = lane >> 4;
    // dense streaming base: this wave's 2 row-blocks (32 rows) in k-step-major layout
    const u16* pA = Ab + (size_t)(mgrp * 32 + w * 2) * 8192 + lane * 8;

    f32x4 acc[2][8];
    #pragma unroll
    for (int i = 0; i < 2; ++i)
        #pragma unroll
        for (int j = 0; j < 8; ++j) acc[i][j] = f32x4{0.f, 0.f, 0.f, 0.f};

    s16x8 aX[2], aY[2];

#define LOADA(buf, ks) {                                                   \
    buf[0] = *(const s16x8*)(pA + (size_t)(ks) * 512);                     \
    buf[1] = *(const s16x8*)(pA + 8192 + (size_t)(ks) * 512); }

#define KSTEP(cur, pre, ks) {                                              \
    if ((ks) + 1 < 16) LOADA(pre, (ks) + 1)                                \
    const int g = (ks) * 4 + q;                                            \
    const int pgo = ((g & 56) | ((g & 7) ^ (fr & 7))) * 8;                 \
    s16x8 bfr[4];                                                          \
    _Pragma("unroll")                                                      \
    for (int nj = 0; nj < 4; ++nj)                                         \
        bfr[nj] = *(const s16x8*)&pool[(nj * 16 + fr) * 512 + pgo];        \
    _Pragma("unroll")                                                      \
    for (int nj = 0; nj < 4; ++nj) {                                       \
        acc[0][nj] = mfma16(cur[0], bfr[nj], acc[0][nj]);                  \
        acc[1][nj] = mfma16(cur[1], bfr[nj], acc[1][nj]); }                \
    _Pragma("unroll")                                                      \
    for (int nj = 0; nj < 4; ++nj)                                         \
        bfr[nj] = *(const s16x8*)&pool[((nj + 4) * 16 + fr) * 512 + pgo];  \
    _Pragma("unroll")                                                      \
    for (int nj = 0; nj < 4; ++nj) {                                       \
        acc[0][nj + 4] = mfma16(cur[0], bfr[nj], acc[0][nj + 4]);          \
        acc[1][nj + 4] = mfma16(cur[1], bfr[nj], acc[1][nj + 4]); } }

    LOADA(aX, 0)
    KSTEP(aX, aY, 0)  KSTEP(aY, aX, 1)  KSTEP(aX, aY, 2)  KSTEP(aY, aX, 3)
    KSTEP(aX, aY, 4)  KSTEP(aY, aX, 5)  KSTEP(aX, aY, 6)  KSTEP(aY, aX, 7)
    KSTEP(aX, aY, 8)  KSTEP(aY, aX, 9)  KSTEP(aX, aY, 10) KSTEP(aY, aX, 11)
    KSTEP(aX, aY, 12) KSTEP(aY, aX, 13) KSTEP(aX, aY, 14) KSTEP(aY, aX, 15)

#undef LOADA
#undef KSTEP

    // ---- epilogue: wave-private LDS transpose (XOR-swizzled) -> coalesced stores ----
    __syncthreads();                              // all waves done reading the B panel
    u16* outp          = (nblk < 4) ? Qb : (nblk < 8 ? Kb : Vb);
    const float* biasp = (nblk < 4) ? bq : (nblk < 8 ? bk : bv);
    const int nn0 = n0 & 511;
    const int c = lane & 15;
    u16* ep = pool + w * 4096;                    // wave-private [32][128] u16 = 8 KB

    float bias[8];
    #pragma unroll
    for (int nj = 0; nj < 8; ++nj) bias[nj] = biasp[nn0 + nj * 16 + c];

    // physical granule = logical ^ ((row>>2)&3); for row=mi*16+q*4+p that is ^q
    #pragma unroll
    for (int mi = 0; mi < 2; ++mi)
        #pragma unroll
        for (int nj = 0; nj < 8; ++nj)
            #pragma unroll
            for (int p = 0; p < 4; ++p)
                ep[(mi * 16 + q * 4 + p) * 128 + (((nj * 2 + (c >> 3)) ^ q) * 8 + (c & 7))] =
                    f2bf(acc[mi][nj][p] + bias[nj]);

    // read back: 4 rows x 256B per instruction; granule c at row rl lives at c^((rl>>2)&3)
    #pragma unroll
    for (int rr = 0; rr < 8; ++rr) {
        int rl = rr * 4 + q;
        s16x8 v = *(const s16x8*)&ep[rl * 128 + (c ^ (rr & 3)) * 8];
        int grow = mgrp * 512 + w * 32 + rl;
        if (grow < NR)
            *(s16x8*)&outp[(size_t)grow * D_ + nn0 + c * 8] = v;
    }
}

// ---------------- fallback fused QKV GEMM (fp32 in, cvt in staging) ----------------
__global__ __launch_bounds__(256) void qkv_gemm_4715(
    const float* __restrict__ temporal, const float* __restrict__ others,
    const float* __restrict__ Wq, const float* __restrict__ bq,
    const float* __restrict__ Wk, const float* __restrict__ bk,
    const float* __restrict__ Wv, const float* __restrict__ bv,
    u16* __restrict__ Qb, u16* __restrict__ Kb, u16* __restrict__ Vb)
{
    __shared__ __align__(16) u16 As[128][72];
    __shared__ __align__(16) u16 Bs[128][72];
    const int tid  = threadIdx.x;
    const int lane = tid & 63;
    const int wave = tid >> 6;
    const int wr = wave >> 1, wc = wave & 1;
    const int m0 = blockIdx.x * 128;
    const int n0 = blockIdx.y * 128;

    const float* arow[4];
    #pragma unroll
    for (int i = 0; i < 4; ++i) {
        int r = m0 + (tid >> 3) + i * 32;
        if (r >= NR) r = 0;
        arow[i] = a_src_row(r, temporal, others);
    }
    const float* brow[4];
    #pragma unroll
    for (int i = 0; i < 4; ++i) {
        int n = n0 + (tid >> 3) + i * 32;
        const float* W = (n < 512) ? Wq : (n < 1024 ? Wk : Wv);
        brow[i] = W + (size_t)(n & 511) * D_;
    }
    const int acol = (tid & 7) * 8;
    const int srow = tid >> 3;

    f32x4 acc[4][4];
    #pragma unroll
    for (int i = 0; i < 4; ++i)
        #pragma unroll
        for (int j = 0; j < 4; ++j) acc[i][j] = f32x4{0.f, 0.f, 0.f, 0.f};

    for (int k0 = 0; k0 < 512; k0 += 64) {
        #pragma unroll
        for (int i = 0; i < 4; ++i) {
            *(s16x8*)&As[srow + i * 32][acol] = cvt8(arow[i] + k0 + acol);
            *(s16x8*)&Bs[srow + i * 32][acol] = cvt8(brow[i] + k0 + acol);
        }
        __syncthreads();
        #pragma unroll
        for (int kk = 0; kk < 64; kk += 32) {
            const int kc = kk + (lane >> 4) * 8;
            const int fr = lane & 15;
            s16x8 af[4], bfr[4];
            #pragma unroll
            for (int i = 0; i < 4; ++i) af[i]  = *(const s16x8*)&As[wr * 64 + i * 16 + fr][kc];
            #pragma unroll
            for (int j = 0; j < 4; ++j) bfr[j] = *(const s16x8*)&Bs[wc * 64 + j * 16 + fr][kc];
            #pragma unroll
            for (int i = 0; i < 4; ++i)
                #pragma unroll
                for (int j = 0; j < 4; ++j)
                    acc[i][j] = mfma16(af[i], bfr[j], acc[i][j]);
        }
        __syncthreads();
    }
    const int q = lane >> 4, c = lane & 15;
    #pragma unroll
    for (int j = 0; j < 4; ++j) {
        int n = n0 + wc * 64 + j * 16 + c;
        u16* outp          = (n < 512) ? Qb : (n < 1024 ? Kb : Vb);
        const float* biasp = (n < 512) ? bq : (n < 1024 ? bk : bv);
        int nn = n & 511;
        float bias = biasp[nn];
        #pragma unroll
        for (int i = 0; i < 4; ++i) {
            int rb = m0 + wr * 64 + i * 16 + q * 4;
            #pragma unroll
            for (int p = 0; p < 4; ++p) {
                int r = rb + p;
                if (r < NR) outp[(size_t)r * D_ + nn] = f2bf(acc[i][j][p] + bias);
            }
        }
    }
}

// ---------------- temporal attention (MFMA, M padded 8->16, N padded 72->80/96) ----------------
__global__ __launch_bounds__(256) void temporal_attn_4715(
    const u16* __restrict__ Qb, const u16* __restrict__ Kb, const u16* __restrict__ Vb,
    float* __restrict__ out)
{
    const int blk = blockIdx.x;           // ((b*4 + hp)*32 + lc)
    const int lc = blk & 31;
    const int hp = (blk >> 5) & 3;
    const int b  = blk >> 7;
    const int tid = threadIdx.x, lane = tid & 63, w = tid >> 6;
    const int q = lane >> 4, c = lane & 15;

    __shared__ __align__(16) u16 KtsS[2][64][72];   // cross-wave, written once
    __shared__ __align__(16) u16 VtsS[2][64][96];   // cross-wave, written once
    __shared__ __align__(16) u16 KttW[4][8][72];    // wave-private
    __shared__ __align__(16) u16 VttW[4][64][8];    // wave-private
    __shared__ __align__(16) u16 Pw[4][16][104];    // wave-private (pad cols written once)

    const size_t srowbase = (size_t)TROWS + (size_t)b * 72 + 8;
    for (int cch = tid; cch < 1024; cch += 256) {
        int hh = cch >> 9;
        int o  = (cch >> 3) & 63;
        int d8 = (cch & 7) * 8;
        int hbase = (hp * 2 + hh) * 64;
        *(s16x8*)&KtsS[hh][o][d8] = *(const s16x8*)&Kb[(srowbase + o) * D_ + hbase + d8];
        s16x8 vv = *(const s16x8*)&Vb[(srowbase + o) * D_ + hbase + d8];
        #pragma unroll
        for (int jj = 0; jj < 8; ++jj) VtsS[hh][d8 + jj][8 + o] = (u16)vv[jj];
    }
    for (int z = tid; z < 2 * 64 * 24; z += 256) {
        int hh = z / (64 * 24); int rem = z - hh * 64 * 24;
        VtsS[hh][rem / 24][72 + rem % 24] = 0;
    }
    for (int z = tid; z < 4 * 16 * 24; z += 256) {
        int ww = z / (16 * 24); int rem = z - ww * 16 * 24;
        Pw[ww][rem / 24][80 + rem % 24] = 0;
    }
    __syncthreads();    // the ONLY barrier: everything below is wave-private

    const float scale = 0.125f;
    for (int ti = 0; ti < 8; ++ti) {
        const int tsk = w + 4 * ti;               // 0..31
        const int hh = tsk >> 4;
        const int il = tsk & 15;
        const int l  = lc * 16 + il;
        const int h  = hp * 2 + hh;
        const int hbase = h * 64;
        const size_t rbase = ((size_t)b * 512 + l) * 8;

        { // stage Ktt (8x64) for this wave
            int m = lane >> 3, d8 = (lane & 7) * 8;
            *(s16x8*)&KttW[w][m][d8] = *(const s16x8*)&Kb[(rbase + m) * D_ + hbase + d8];
        }
        { // stage Vtt^T (64 x 8)
            #pragma unroll
            for (int m = 0; m < 8; ++m)
                VttW[w][lane][m] = Vb[(rbase + m) * D_ + hbase + lane];
        }
        const int mq = (c < 8) ? c : (c - 8);
        s16x8 aq0 = *(const s16x8*)&Qb[(rbase + mq) * D_ + hbase + q * 8];
        s16x8 aq1 = *(const s16x8*)&Qb[(rbase + mq) * D_ + hbase + 32 + q * 8];
        asm volatile("s_waitcnt lgkmcnt(0)" ::: "memory");  // in-wave RAW on KttW/VttW

        // QK^T: 5 n-tiles of 16, k = 64 (2 steps)
        f32x4 sacc[5];
        #pragma unroll
        for (int j = 0; j < 5; ++j) sacc[j] = f32x4{0.f, 0.f, 0.f, 0.f};
        #pragma unroll
        for (int j = 0; j < 5; ++j) {
            int g = j * 16 + c;
            const u16* kp0;
            if (g < 8) kp0 = &KttW[w][g][0];
            else { int o = g - 8; if (o > 63) o = 63; kp0 = &KtsS[hh][o][0]; }
            s16x8 b0 = *(const s16x8*)(kp0 + q * 8);
            s16x8 b1 = *(const s16x8*)(kp0 + 32 + q * 8);
            sacc[j] = mfma16(aq0, b0, sacc[j]);
            sacc[j] = mfma16(aq1, b1, sacc[j]);
        }
        float ev[5][4];
        float mx[4] = {-1e30f, -1e30f, -1e30f, -1e30f};
        #pragma unroll
        for (int j = 0; j < 5; ++j) {
            bool valid = (j < 4) || (c < 8);
            #pragma unroll
            for (int p = 0; p < 4; ++p) {
                float v = sacc[j][p] * scale;
                ev[j][p] = valid ? v : -1e30f;
                if (valid) mx[p] = fmaxf(mx[p], v);
            }
        }
        #pragma unroll
        for (int msk = 1; msk < 16; msk <<= 1)
            #pragma unroll
            for (int p = 0; p < 4; ++p)
                mx[p] = fmaxf(mx[p], __shfl_xor(mx[p], msk, 16));
        float sm[4] = {0.f, 0.f, 0.f, 0.f};
        #pragma unroll
        for (int j = 0; j < 5; ++j) {
            bool valid = (j < 4) || (c < 8);
            #pragma unroll
            for (int p = 0; p < 4; ++p) {
                float e = valid ? __expf(ev[j][p] - mx[p]) : 0.f;
                ev[j][p] = e;
                sm[p] += e;
            }
        }
        #pragma unroll
        for (int msk = 1; msk < 16; msk <<= 1)
            #pragma unroll
            for (int p = 0; p < 4; ++p)
                sm[p] += __shfl_xor(sm[p], msk, 16);
        float inv[4];
        #pragma unroll
        for (int p = 0; p < 4; ++p) inv[p] = 1.0f / sm[p];

        float* attnp = out + TATTN_OFF + ((((size_t)b * 8 + h) * 512 + l) * 8) * 72;
        #pragma unroll
        for (int j = 0; j < 5; ++j) {
            #pragma unroll
            for (int p = 0; p < 4; ++p) {
                int row = q * 4 + p;
                int col = j * 16 + c;
                float pv = ev[j][p] * inv[p];
                Pw[w][row][col] = f2bf(pv);
                if (row < 8 && col < 72)
                    attnp[(size_t)row * 72 + col] = pv;
            }
        }
        asm volatile("s_waitcnt lgkmcnt(0)" ::: "memory");  // in-wave RAW on Pw

        f32x4 oacc[4];
        #pragma unroll
        for (int j = 0; j < 4; ++j) oacc[j] = f32x4{0.f, 0.f, 0.f, 0.f};
        #pragma unroll
        for (int ks = 0; ks < 3; ++ks) {
            s16x8 ap = *(const s16x8*)&Pw[w][c][ks * 32 + q * 8];
            #pragma unroll
            for (int j = 0; j < 4; ++j) {
                int d = j * 16 + c;
                int kb = ks * 32 + q * 8;
                const u16* vp = (kb == 0) ? &VttW[w][d][0] : &VtsS[hh][d][kb];
                s16x8 bp = *(const s16x8*)vp;
                oacc[j] = mfma16(ap, bp, oacc[j]);
            }
        }
        float* toutp = out + (((size_t)b * 513 + l + 1) * 8) * 512 + hbase;
        #pragma unroll
        for (int j = 0; j < 4; ++j) {
            int d = j * 16 + c;
            #pragma unroll
            for (int p = 0; p < 4; ++p) {
                int row = q * 4 + p;
                if (row < 8)
                    toutp[(size_t)row * 512 + d] = oacc[j][p];
            }
        }
    }
}

// ---------------- others (ss) attention ----------------
__global__ __launch_bounds__(256) void others_attn_4715(
    const u16* __restrict__ Qb, const u16* __restrict__ Kb, const u16* __restrict__ Vb,
    float* __restrict__ out)
{
    const int blk = blockIdx.x;       // ((b*8 + h)*4 + mq)
    const int mq = blk & 3;
    const int h  = (blk >> 2) & 7;
    const int b  = blk >> 5;
    const int tid = threadIdx.x;
    const int hbase = h * 64;
    const size_t rbase = (size_t)TROWS + (size_t)b * 72;

    __shared__ float Qo[18][68];
    __shared__ float Ko[72][68];
    __shared__ float VoT[64][84];
    __shared__ float S[18][80];

    for (int e = tid; e < 72 * 64; e += 256) {
        int r = e >> 6, d = e & 63;
        Ko[r][d]  = bf2f(Kb[(rbase + r) * D_ + hbase + d]);
        VoT[d][r] = bf2f(Vb[(rbase + r) * D_ + hbase + d]);
    }
    for (int e = tid; e < 18 * 64; e += 256) {
        int r = e >> 6, d = e & 63;
        Qo[r][d] = bf2f(Qb[(rbase + mq * 18 + r) * D_ + hbase + d]);
    }
    for (int e = tid; e < 64 * 12; e += 256) VoT[e / 12][72 + e % 12] = 0.f;
    __syncthreads();

    for (int e = tid; e < 18 * 72; e += 256) {
        int m = e / 72, n = e - m * 72;
        const float* qp = Qo[m];
        const float* kp = Ko[n];
        float s = 0.f;
        #pragma unroll
        for (int d = 0; d < 64; ++d) s += qp[d] * kp[d];
        S[m][n] = s * 0.125f;
    }
    __syncthreads();
    if (tid < 18) {
        int m = tid;
        float mx = -1e30f;
        for (int n = 0; n < 72; ++n) mx = fmaxf(mx, S[m][n]);
        float sm = 0.f;
        for (int n = 0; n < 72; ++n) { float e = __expf(S[m][n] - mx); S[m][n] = e; sm += e; }
        float inv = 1.f / sm;
        size_t arow = OATTN_OFF + (((size_t)b * 8 + h) * 72 + (mq * 18 + m)) * 72;
        for (int n = 0; n < 72; ++n) {
            float p = S[m][n] * inv; S[m][n] = p;
            out[arow + n] = p;
        }
    }
    __syncthreads();
    // others_ = others.reshape(B,-1,D), no transpose: (h,n,d) -> i=h*9+n/8, j=(n%8)*64+d
    for (int e = tid; e < 18 * 64; e += 256) {
        int m = e >> 6, d = e & 63;
        float o = 0.f;
        #pragma unroll
        for (int n = 0; n < 72; ++n) o += S[m][n] * VoT[d][n];
        int nq = mq * 18 + m;
        int i  = h * 9 + (nq >> 3);
        int jj = (nq & 7) * 64 + d;
        size_t oaddr;
        if (i < 8) oaddr = ((size_t)b * 513 * 8 + i) * 512 + jj;
        else       oaddr = OOUT_OFF + ((size_t)b * 64 + (i - 8)) * 512 + jj;
        out[oaddr] = o;
    }
}

extern "C" void kernel_launch(void* const* d_in, const int* in_sizes, int n_in,
                              void* d_out, int out_size, void* d_ws, size_t ws_size,
                              hipStream_t stream) {
    const float* temporal = (const float*)d_in[0];
    const float* others   = (const float*)d_in[1];
    const float* Wq = (const float*)d_in[2];
    const float* bq = (const float*)d_in[3];
    const float* Wk = (const float*)d_in[4];
    const float* bk = (const float*)d_in[5];
    const float* Wv = (const float*)d_in[6];
    const float* bv = (const float*)d_in[7];
    float* outp = (float*)d_out;
    u16* Qb = (u16*)d_ws;
    u16* Kb = Qb + (size_t)NR * D_;
    u16* Vb = Kb + (size_t)NR * D_;
    u16* Ab = Vb + (size_t)NR * D_;
    u16* Wb = Ab + (size_t)NRP * D_;
    const size_t need = ((size_t)3 * NR * D_ + (size_t)NRP * D_ + (size_t)1536 * D_) * 2;

    if (ws_size >= need) {
        hipLaunchKernelGGL(prep_4715, dim3((NRP + 1536) * 64 / 256), dim3(256), 0, stream,
                           temporal, others, Wq, Wk, Wv, Ab, Wb);
        hipLaunchKernelGGL(qkv_gemm2_4715, dim3(66 * 12), dim3(1024), 0, stream,
                           Ab, Wb, bq, bk, bv, Qb, Kb, Vb);
    } else {
        hipLaunchKernelGGL(qkv_gemm_4715, dim3(261, 12), dim3(256), 0, stream,
                           temporal, others, Wq, bq, Wk, bk, Wv, bv, Qb, Kb, Vb);
    }
    hipLaunchKernelGGL(temporal_attn_4715, dim3(1024), dim3(256), 0, stream, Qb, Kb, Vb, outp);
    hipLaunchKernelGGL(others_attn_4715, dim3(256), dim3(256), 0, stream, Qb, Kb, Vb, outp);
}

// Round 8
// 347.582 us; speedup vs baseline: 1.1896x; 1.0097x over previous
//
#include <hip/hip_runtime.h>
#include <hip/hip_bf16.h>

typedef unsigned short u16;
typedef unsigned int   u32;
typedef short  s16x8 __attribute__((ext_vector_type(8)));
typedef __bf16 bf16x8 __attribute__((ext_vector_type(8)));
typedef float  f32x4 __attribute__((ext_vector_type(4)));

#define D_ 512
#define NR 33344          // B*L*M + B*72 = 32768 + 576
#define NRP 33792         // padded to 66*512 (block = 512 rows)
#define TROWS 32768       // temp rows
#define TOUT_OFF  0UL
#define OOUT_OFF  16809984UL
#define TATTN_OFF 17072128UL
#define OATTN_OFF 35946496UL

__device__ __forceinline__ float bf2f(u16 x) {
    union { u32 u; float f; } v; v.u = ((u32)x) << 16; return v.f;
}
__device__ __forceinline__ u16 f2bf(float f) {
    union { float f; u32 u; } v; v.f = f;
    u32 u = v.u;
    return (u16)((u + 0x7fffu + ((u >> 16) & 1u)) >> 16);
}
// load 8 contiguous fp32, round-to-nearest-even to bf16x8
__device__ __forceinline__ s16x8 cvt8(const float* p) {
    float4 a = *(const float4*)p;
    float4 b = *(const float4*)(p + 4);
    s16x8 r;
    r[0] = (short)f2bf(a.x); r[1] = (short)f2bf(a.y);
    r[2] = (short)f2bf(a.z); r[3] = (short)f2bf(a.w);
    r[4] = (short)f2bf(b.x); r[5] = (short)f2bf(b.y);
    r[6] = (short)f2bf(b.z); r[7] = (short)f2bf(b.w);
    return r;
}
__device__ __forceinline__ f32x4 mfma16(s16x8 a, s16x8 b, f32x4 c) {
    return __builtin_amdgcn_mfma_f32_16x16x32_bf16(
        __builtin_bit_cast(bf16x8, a), __builtin_bit_cast(bf16x8, b), c, 0, 0, 0);
}
__device__ __forceinline__ void gload_lds16(const u16* g, u16* l) {
    __builtin_amdgcn_global_load_lds(
        (const __attribute__((address_space(1))) void*)g,
        (__attribute__((address_space(3))) void*)l, 16, 0, 0);
}

// row r of the fused A matrix -> source row pointer (fp32)
__device__ __forceinline__ const float* a_src_row(int r, const float* temporal, const float* others) {
    if (r < TROWS) {
        int b = r >> 12;
        return temporal + (size_t)(r + 8 * (b + 1)) * D_;
    }
    int rr = r - TROWS;
    int b = rr / 72, j = rr - b * 72;
    return (j < 8) ? (temporal + (size_t)(b * 4104 + j) * D_)
                   : (others   + (size_t)(b * 64 + j - 8) * D_);
}

// ---------------- pre-pass: fp32 -> bf16 ----------------
// A stored K-STEP-MAJOR: element (row,k) at Ab[(row>>4)*8192 + ks*512 + q*128 + (row&15)*8 + e]
// with k = ks*32 + q*8 + e.  Threads iterate over the OUTPUT offset (idx*8 -> perfectly
// coalesced sequential 16B stores) and compute the matching fp32 source chunk (32B reads,
// sector-complete within a wave).
__global__ __launch_bounds__(256) void prep_4715(
    const float* __restrict__ temporal, const float* __restrict__ others,
    const float* __restrict__ Wq, const float* __restrict__ Wk, const float* __restrict__ Wv,
    u16* __restrict__ Ab, u16* __restrict__ Wb)
{
    int idx = blockIdx.x * 256 + threadIdx.x;   // one thread = 8 u16 out
    if (idx < NRP * 64) {
        // output-linear mapping
        int rb  = idx >> 10;            // 1024 chunks per 16-row block (8192 u16)
        int rem = idx & 1023;
        int ks  = rem >> 6;             // 64 chunks per k-step slab (512 u16)
        int qq  = (rem >> 4) & 3;       // 16 chunks per q slab (128 u16)
        int ri  = rem & 15;             // 1 chunk per row (8 u16)
        int r   = rb * 16 + ri;
        u16* dst = Ab + (size_t)idx * 8;
        if (r >= NR) {
            u32* d32 = (u32*)dst;
            d32[0] = 0; d32[1] = 0; d32[2] = 0; d32[3] = 0;
            return;
        }
        *(s16x8*)dst = cvt8(a_src_row(r, temporal, others) + ks * 32 + qq * 8);
    } else {
        int r  = idx >> 6;
        int ch = (idx & 63) * 8;
        if (r >= NRP + 1536) return;
        int n = r - NRP;
        const float* W = (n < 512) ? Wq : (n < 1024 ? Wk : Wv);
        *(s16x8*)(Wb + (size_t)n * D_ + ch) = cvt8(W + (size_t)(n & 511) * D_ + ch);
    }
}

// ---------------- QKV GEMM: resident-B-panel, streaming-A, 8 waves x 64 rows ----------------
// Round-7 structure with ONE variable changed: wave owns 64 rows (acc[4][8]) instead of 32.
// Rationale (measured): with 16 waves all reading the same 128 B-cols, LDS reads were
// 128 KB/CU/kstep (~1540 cyc at 85 B/cyc) vs 310 cyc of MFMA -- LDS-BW-bound 5x over.
// 64-row waves halve B-read traffic per FLOP: 64 KB/CU/kstep (~770 cyc). 512 threads,
// ~200 VGPR, 2 waves/SIMD, 1 block/CU, same grid/swizzle/A-stream/epilogue as round 7.
__global__ __launch_bounds__(512, 2) void qkv_gemm2_4715(
    const u16* __restrict__ Ab, const u16* __restrict__ Wb,
    const float* __restrict__ bq, const float* __restrict__ bk, const float* __restrict__ bv,
    u16* __restrict__ Qb, u16* __restrict__ Kb, u16* __restrict__ Vb)
{
    __shared__ __align__(16) u16 pool[65536];     // 128 KB: B panel, then epilogue buffer
    const int tid  = threadIdx.x;
    const int lane = tid & 63;
    const int w    = tid >> 6;                    // 8 waves, each owns 64 rows

    // XCD swizzle: 792 blocks = 8 * 99 exactly -> bijective chunking; nblk fastest
    int orig = blockIdx.x;
    int gx = (orig & 7) * 99 + (orig >> 3);
    const int nblk = gx % 12;
    const int mgrp = gx / 12;
    const int n0 = nblk * 128;

    // ---- stage B panel once: wave w loads rows w*16..w*16+15 (1 KB row each) ----
    // LDS[r][g] = global[r][(g&56) | ((g&7)^(r&7))]  (granule = 8 u16 = 16B)
    #pragma unroll
    for (int rr = 0; rr < 16; ++rr) {
        int r  = w * 16 + rr;
        int sg = (lane & 56) | ((lane & 7) ^ (r & 7));
        gload_lds16(Wb + (size_t)(n0 + r) * D_ + sg * 8, pool + r * 512);
    }
    asm volatile("s_waitcnt vmcnt(0)" ::: "memory");
    __builtin_amdgcn_sched_barrier(0);
    __syncthreads();

    const int fr = lane & 15;
    const int q  = lane >> 4;
    // dense streaming base: this wave's 4 row-blocks (64 rows) in k-step-major layout
    const u16* pA = Ab + (size_t)(mgrp * 32 + w * 4) * 8192 + lane * 8;

    f32x4 acc[4][8];
    #pragma unroll
    for (int i = 0; i < 4; ++i)
        #pragma unroll
        for (int j = 0; j < 8; ++j) acc[i][j] = f32x4{0.f, 0.f, 0.f, 0.f};

    s16x8 aX[4], aY[4];

#define LOADA(buf, ks) {                                                   \
    _Pragma("unroll")                                                      \
    for (int mi = 0; mi < 4; ++mi)                                         \
        buf[mi] = *(const s16x8*)(pA + (size_t)mi * 8192 + (ks) * 512); }

#define KSTEP(cur, pre, ks) {                                              \
    if ((ks) + 1 < 16) LOADA(pre, (ks) + 1)                                \
    const int g = (ks) * 4 + q;                                            \
    const int pgo = ((g & 56) | ((g & 7) ^ (fr & 7))) * 8;                 \
    s16x8 bfr[4];                                                          \
    _Pragma("unroll")                                                      \
    for (int nj = 0; nj < 4; ++nj)                                         \
        bfr[nj] = *(const s16x8*)&pool[(nj * 16 + fr) * 512 + pgo];        \
    _Pragma("unroll")                                                      \
    for (int mi = 0; mi < 4; ++mi)                                         \
        _Pragma("unroll")                                                  \
        for (int nj = 0; nj < 4; ++nj)                                     \
            acc[mi][nj] = mfma16(cur[mi], bfr[nj], acc[mi][nj]);           \
    _Pragma("unroll")                                                      \
    for (int nj = 0; nj < 4; ++nj)                                         \
        bfr[nj] = *(const s16x8*)&pool[((nj + 4) * 16 + fr) * 512 + pgo];  \
    _Pragma("unroll")                                                      \
    for (int mi = 0; mi < 4; ++mi)                                         \
        _Pragma("unroll")                                                  \
        for (int nj = 0; nj < 4; ++nj)                                     \
            acc[mi][nj + 4] = mfma16(cur[mi], bfr[nj], acc[mi][nj + 4]); }

    LOADA(aX, 0)
    KSTEP(aX, aY, 0)  KSTEP(aY, aX, 1)  KSTEP(aX, aY, 2)  KSTEP(aY, aX, 3)
    KSTEP(aX, aY, 4)  KSTEP(aY, aX, 5)  KSTEP(aX, aY, 6)  KSTEP(aY, aX, 7)
    KSTEP(aX, aY, 8)  KSTEP(aY, aX, 9)  KSTEP(aX, aY, 10) KSTEP(aY, aX, 11)
    KSTEP(aX, aY, 12) KSTEP(aY, aX, 13) KSTEP(aX, aY, 14) KSTEP(aY, aX, 15)

#undef LOADA
#undef KSTEP

    // ---- epilogue: wave-private LDS transpose (XOR-swizzled) -> coalesced stores ----
    __syncthreads();                              // all waves done reading the B panel
    u16* outp          = (nblk < 4) ? Qb : (nblk < 8 ? Kb : Vb);
    const float* biasp = (nblk < 4) ? bq : (nblk < 8 ? bk : bv);
    const int nn0 = n0 & 511;
    const int c = lane & 15;
    u16* ep = pool + w * 8192;                    // wave-private [64][128] u16 = 16 KB

    float bias[8];
    #pragma unroll
    for (int nj = 0; nj < 8; ++nj) bias[nj] = biasp[nn0 + nj * 16 + c];

    // physical granule = logical ^ ((row>>2)&3); for row=mi*16+q*4+p that is ^q
    #pragma unroll
    for (int mi = 0; mi < 4; ++mi)
        #pragma unroll
        for (int nj = 0; nj < 8; ++nj)
            #pragma unroll
            for (int p = 0; p < 4; ++p)
                ep[(mi * 16 + q * 4 + p) * 128 + (((nj * 2 + (c >> 3)) ^ q) * 8 + (c & 7))] =
                    f2bf(acc[mi][nj][p] + bias[nj]);

    // read back: 4 rows x 256B per instruction; granule c at row rl lives at c^((rl>>2)&3)
    #pragma unroll
    for (int rr = 0; rr < 16; ++rr) {
        int rl = rr * 4 + q;
        s16x8 v = *(const s16x8*)&ep[rl * 128 + (c ^ (rr & 3)) * 8];
        int grow = mgrp * 512 + w * 64 + rl;
        if (grow < NR)
            *(s16x8*)&outp[(size_t)grow * D_ + nn0 + c * 8] = v;
    }
}

// ---------------- fallback fused QKV GEMM (fp32 in, cvt in staging) ----------------
__global__ __launch_bounds__(256) void qkv_gemm_4715(
    const float* __restrict__ temporal, const float* __restrict__ others,
    const float* __restrict__ Wq, const float* __restrict__ bq,
    const float* __restrict__ Wk, const float* __restrict__ bk,
    const float* __restrict__ Wv, const float* __restrict__ bv,
    u16* __restrict__ Qb, u16* __restrict__ Kb, u16* __restrict__ Vb)
{
    __shared__ __align__(16) u16 As[128][72];
    __shared__ __align__(16) u16 Bs[128][72];
    const int tid  = threadIdx.x;
    const int lane = tid & 63;
    const int wave = tid >> 6;
    const int wr = wave >> 1, wc = wave & 1;
    const int m0 = blockIdx.x * 128;
    const int n0 = blockIdx.y * 128;

    const float* arow[4];
    #pragma unroll
    for (int i = 0; i < 4; ++i) {
        int r = m0 + (tid >> 3) + i * 32;
        if (r >= NR) r = 0;
        arow[i] = a_src_row(r, temporal, others);
    }
    const float* brow[4];
    #pragma unroll
    for (int i = 0; i < 4; ++i) {
        int n = n0 + (tid >> 3) + i * 32;
        const float* W = (n < 512) ? Wq : (n < 1024 ? Wk : Wv);
        brow[i] = W + (size_t)(n & 511) * D_;
    }
    const int acol = (tid & 7) * 8;
    const int srow = tid >> 3;

    f32x4 acc[4][4];
    #pragma unroll
    for (int i = 0; i < 4; ++i)
        #pragma unroll
        for (int j = 0; j < 4; ++j) acc[i][j] = f32x4{0.f, 0.f, 0.f, 0.f};

    for (int k0 = 0; k0 < 512; k0 += 64) {
        #pragma unroll
        for (int i = 0; i < 4; ++i) {
            *(s16x8*)&As[srow + i * 32][acol] = cvt8(arow[i] + k0 + acol);
            *(s16x8*)&Bs[srow + i * 32][acol] = cvt8(brow[i] + k0 + acol);
        }
        __syncthreads();
        #pragma unroll
        for (int kk = 0; kk < 64; kk += 32) {
            const int kc = kk + (lane >> 4) * 8;
            const int fr = lane & 15;
            s16x8 af[4], bfr[4];
            #pragma unroll
            for (int i = 0; i < 4; ++i) af[i]  = *(const s16x8*)&As[wr * 64 + i * 16 + fr][kc];
            #pragma unroll
            for (int j = 0; j < 4; ++j) bfr[j] = *(const s16x8*)&Bs[wc * 64 + j * 16 + fr][kc];
            #pragma unroll
            for (int i = 0; i < 4; ++i)
                #pragma unroll
                for (int j = 0; j < 4; ++j)
                    acc[i][j] = mfma16(af[i], bfr[j], acc[i][j]);
        }
        __syncthreads();
    }
    const int q = lane >> 4, c = lane & 15;
    #pragma unroll
    for (int j = 0; j < 4; ++j) {
        int n = n0 + wc * 64 + j * 16 + c;
        u16* outp          = (n < 512) ? Qb : (n < 1024 ? Kb : Vb);
        const float* biasp = (n < 512) ? bq : (n < 1024 ? bk : bv);
        int nn = n & 511;
        float bias = biasp[nn];
        #pragma unroll
        for (int i = 0; i < 4; ++i) {
            int rb = m0 + wr * 64 + i * 16 + q * 4;
            #pragma unroll
            for (int p = 0; p < 4; ++p) {
                int r = rb + p;
                if (r < NR) outp[(size_t)r * D_ + nn] = f2bf(acc[i][j][p] + bias);
            }
        }
    }
}

// ---------------- temporal attention (MFMA, M padded 8->16, N padded 72->80/96) ----------------
__global__ __launch_bounds__(256) void temporal_attn_4715(
    const u16* __restrict__ Qb, const u16* __restrict__ Kb, const u16* __restrict__ Vb,
    float* __restrict__ out)
{
    const int blk = blockIdx.x;           // ((b*4 + hp)*32 + lc)
    const int lc = blk & 31;
    const int hp = (blk >> 5) & 3;
    const int b  = blk >> 7;
    const int tid = threadIdx.x, lane = tid & 63, w = tid >> 6;
    const int q = lane >> 4, c = lane & 15;

    __shared__ __align__(16) u16 KtsS[2][64][72];   // cross-wave, written once
    __shared__ __align__(16) u16 VtsS[2][64][96];   // cross-wave, written once
    __shared__ __align__(16) u16 KttW[4][8][72];    // wave-private
    __shared__ __align__(16) u16 VttW[4][64][8];    // wave-private
    __shared__ __align__(16) u16 Pw[4][16][104];    // wave-private (pad cols written once)

    const size_t srowbase = (size_t)TROWS + (size_t)b * 72 + 8;
    for (int cch = tid; cch < 1024; cch += 256) {
        int hh = cch >> 9;
        int o  = (cch >> 3) & 63;
        int d8 = (cch & 7) * 8;
        int hbase = (hp * 2 + hh) * 64;
        *(s16x8*)&KtsS[hh][o][d8] = *(const s16x8*)&Kb[(srowbase + o) * D_ + hbase + d8];
        s16x8 vv = *(const s16x8*)&Vb[(srowbase + o) * D_ + hbase + d8];
        #pragma unroll
        for (int jj = 0; jj < 8; ++jj) VtsS[hh][d8 + jj][8 + o] = (u16)vv[jj];
    }
    for (int z = tid; z < 2 * 64 * 24; z += 256) {
        int hh = z / (64 * 24); int rem = z - hh * 64 * 24;
        VtsS[hh][rem / 24][72 + rem % 24] = 0;
    }
    for (int z = tid; z < 4 * 16 * 24; z += 256) {
        int ww = z / (16 * 24); int rem = z - ww * 16 * 24;
        Pw[ww][rem / 24][80 + rem % 24] = 0;
    }
    __syncthreads();    // the ONLY barrier: everything below is wave-private

    const float scale = 0.125f;
    for (int ti = 0; ti < 8; ++ti) {
        const int tsk = w + 4 * ti;               // 0..31
        const int hh = tsk >> 4;
        const int il = tsk & 15;
        const int l  = lc * 16 + il;
        const int h  = hp * 2 + hh;
        const int hbase = h * 64;
        const size_t rbase = ((size_t)b * 512 + l) * 8;

        { // stage Ktt (8x64) for this wave
            int m = lane >> 3, d8 = (lane & 7) * 8;
            *(s16x8*)&KttW[w][m][d8] = *(const s16x8*)&Kb[(rbase + m) * D_ + hbase + d8];
        }
        { // stage Vtt^T (64 x 8)
            #pragma unroll
            for (int m = 0; m < 8; ++m)
                VttW[w][lane][m] = Vb[(rbase + m) * D_ + hbase + lane];
        }
        const int mq = (c < 8) ? c : (c - 8);
        s16x8 aq0 = *(const s16x8*)&Qb[(rbase + mq) * D_ + hbase + q * 8];
        s16x8 aq1 = *(const s16x8*)&Qb[(rbase + mq) * D_ + hbase + 32 + q * 8];
        asm volatile("s_waitcnt lgkmcnt(0)" ::: "memory");  // in-wave RAW on KttW/VttW

        // QK^T: 5 n-tiles of 16, k = 64 (2 steps)
        f32x4 sacc[5];
        #pragma unroll
        for (int j = 0; j < 5; ++j) sacc[j] = f32x4{0.f, 0.f, 0.f, 0.f};
        #pragma unroll
        for (int j = 0; j < 5; ++j) {
            int g = j * 16 + c;
            const u16* kp0;
            if (g < 8) kp0 = &KttW[w][g][0];
            else { int o = g - 8; if (o > 63) o = 63; kp0 = &KtsS[hh][o][0]; }
            s16x8 b0 = *(const s16x8*)(kp0 + q * 8);
            s16x8 b1 = *(const s16x8*)(kp0 + 32 + q * 8);
            sacc[j] = mfma16(aq0, b0, sacc[j]);
            sacc[j] = mfma16(aq1, b1, sacc[j]);
        }
        float ev[5][4];
        float mx[4] = {-1e30f, -1e30f, -1e30f, -1e30f};
        #pragma unroll
        for (int j = 0; j < 5; ++j) {
            bool valid = (j < 4) || (c < 8);
            #pragma unroll
            for (int p = 0; p < 4; ++p) {
                float v = sacc[j][p] * scale;
                ev[j][p] = valid ? v : -1e30f;
                if (valid) mx[p] = fmaxf(mx[p], v);
            }
        }
        #pragma unroll
        for (int msk = 1; msk < 16; msk <<= 1)
            #pragma unroll
            for (int p = 0; p < 4; ++p)
                mx[p] = fmaxf(mx[p], __shfl_xor(mx[p], msk, 16));
        float sm[4] = {0.f, 0.f, 0.f, 0.f};
        #pragma unroll
        for (int j = 0; j < 5; ++j) {
            bool valid = (j < 4) || (c < 8);
            #pragma unroll
            for (int p = 0; p < 4; ++p) {
                float e = valid ? __expf(ev[j][p] - mx[p]) : 0.f;
                ev[j][p] = e;
                sm[p] += e;
            }
        }
        #pragma unroll
        for (int msk = 1; msk < 16; msk <<= 1)
            #pragma unroll
            for (int p = 0; p < 4; ++p)
                sm[p] += __shfl_xor(sm[p], msk, 16);
        float inv[4];
        #pragma unroll
        for (int p = 0; p < 4; ++p) inv[p] = 1.0f / sm[p];

        float* attnp = out + TATTN_OFF + ((((size_t)b * 8 + h) * 512 + l) * 8) * 72;
        #pragma unroll
        for (int j = 0; j < 5; ++j) {
            #pragma unroll
            for (int p = 0; p < 4; ++p) {
                int row = q * 4 + p;
                int col = j * 16 + c;
                float pv = ev[j][p] * inv[p];
                Pw[w][row][col] = f2bf(pv);
                if (row < 8 && col < 72)
                    attnp[(size_t)row * 72 + col] = pv;
            }
        }
        asm volatile("s_waitcnt lgkmcnt(0)" ::: "memory");  // in-wave RAW on Pw

        f32x4 oacc[4];
        #pragma unroll
        for (int j = 0; j < 4; ++j) oacc[j] = f32x4{0.f, 0.f, 0.f, 0.f};
        #pragma unroll
        for (int ks = 0; ks < 3; ++ks) {
            s16x8 ap = *(const s16x8*)&Pw[w][c][ks * 32 + q * 8];
            #pragma unroll
            for (int j = 0; j < 4; ++j) {
                int d = j * 16 + c;
                int kb = ks * 32 + q * 8;
                const u16* vp = (kb == 0) ? &VttW[w][d][0] : &VtsS[hh][d][kb];
                s16x8 bp = *(const s16x8*)vp;
                oacc[j] = mfma16(ap, bp, oacc[j]);
            }
        }
        float* toutp = out + (((size_t)b * 513 + l + 1) * 8) * 512 + hbase;
        #pragma unroll
        for (int j = 0; j < 4; ++j) {
            int d = j * 16 + c;
            #pragma unroll
            for (int p = 0; p < 4; ++p) {
                int row = q * 4 + p;
                if (row < 8)
                    toutp[(size_t)row * 512 + d] = oacc[j][p];
            }
        }
    }
}

// ---------------- others (ss) attention ----------------
__global__ __launch_bounds__(256) void others_attn_4715(
    const u16* __restrict__ Qb, const u16* __restrict__ Kb, const u16* __restrict__ Vb,
    float* __restrict__ out)
{
    const int blk = blockIdx.x;       // ((b*8 + h)*4 + mq)
    const int mq = blk & 3;
    const int h  = (blk >> 2) & 7;
    const int b  = blk >> 5;
    const int tid = threadIdx.x;
    const int hbase = h * 64;
    const size_t rbase = (size_t)TROWS + (size_t)b * 72;

    __shared__ float Qo[18][68];
    __shared__ float Ko[72][68];
    __shared__ float VoT[64][84];
    __shared__ float S[18][80];

    for (int e = tid; e < 72 * 64; e += 256) {
        int r = e >> 6, d = e & 63;
        Ko[r][d]  = bf2f(Kb[(rbase + r) * D_ + hbase + d]);
        VoT[d][r] = bf2f(Vb[(rbase + r) * D_ + hbase + d]);
    }
    for (int e = tid; e < 18 * 64; e += 256) {
        int r = e >> 6, d = e & 63;
        Qo[r][d] = bf2f(Qb[(rbase + mq * 18 + r) * D_ + hbase + d]);
    }
    for (int e = tid; e < 64 * 12; e += 256) VoT[e / 12][72 + e % 12] = 0.f;
    __syncthreads();

    for (int e = tid; e < 18 * 72; e += 256) {
        int m = e / 72, n = e - m * 72;
        const float* qp = Qo[m];
        const float* kp = Ko[n];
        float s = 0.f;
        #pragma unroll
        for (int d = 0; d < 64; ++d) s += qp[d] * kp[d];
        S[m][n] = s * 0.125f;
    }
    __syncthreads();
    if (tid < 18) {
        int m = tid;
        float mx = -1e30f;
        for (int n = 0; n < 72; ++n) mx = fmaxf(mx, S[m][n]);
        float sm = 0.f;
        for (int n = 0; n < 72; ++n) { float e = __expf(S[m][n] - mx); S[m][n] = e; sm += e; }
        float inv = 1.f / sm;
        size_t arow = OATTN_OFF + (((size_t)b * 8 + h) * 72 + (mq * 18 + m)) * 72;
        for (int n = 0; n < 72; ++n) {
            float p = S[m][n] * inv; S[m][n] = p;
            out[arow + n] = p;
        }
    }
    __syncthreads();
    // others_ = others.reshape(B,-1,D), no transpose: (h,n,d) -> i=h*9+n/8, j=(n%8)*64+d
    for (int e = tid; e < 18 * 64; e += 256) {
        int m = e >> 6, d = e & 63;
        float o = 0.f;
        #pragma unroll
        for (int n = 0; n < 72; ++n) o += S[m][n] * VoT[d][n];
        int nq = mq * 18 + m;
        int i  = h * 9 + (nq >> 3);
        int jj = (nq & 7) * 64 + d;
        size_t oaddr;
        if (i < 8) oaddr = ((size_t)b * 513 * 8 + i) * 512 + jj;
        else       oaddr = OOUT_OFF + ((size_t)b * 64 + (i - 8)) * 512 + jj;
        out[oaddr] = o;
    }
}

extern "C" void kernel_launch(void* const* d_in, const int* in_sizes, int n_in,
                              void* d_out, int out_size, void* d_ws, size_t ws_size,
                              hipStream_t stream) {
    const float* temporal = (const float*)d_in[0];
    const float* others   = (const float*)d_in[1];
    const float* Wq = (const float*)d_in[2];
    const float* bq = (const float*)d_in[3];
    const float* Wk = (const float*)d_in[4];
    const float* bk = (const float*)d_in[5];
    const float* Wv = (const float*)d_in[6];
    const float* bv = (const float*)d_in[7];
    float* outp = (float*)d_out;
    u16* Qb = (u16*)d_ws;
    u16* Kb = Qb + (size_t)NR * D_;
    u16* Vb = Kb + (size_t)NR * D_;
    u16* Ab = Vb + (size_t)NR * D_;
    u16* Wb = Ab + (size_t)NRP * D_;
    const size_t need = ((size_t)3 * NR * D_ + (size_t)NRP * D_ + (size_t)1536 * D_) * 2;

    if (ws_size >= need) {
        hipLaunchKernelGGL(prep_4715, dim3((NRP + 1536) * 64 / 256), dim3(256), 0, stream,
                           temporal, others, Wq, Wk, Wv, Ab, Wb);
        hipLaunchKernelGGL(qkv_gemm2_4715, dim3(66 * 12), dim3(512), 0, stream,
                           Ab, Wb, bq, bk, bv, Qb, Kb, Vb);
    } else {
        hipLaunchKernelGGL(qkv_gemm_4715, dim3(261, 12), dim3(256), 0, stream,
                           temporal, others, Wq, bq, Wk, bk, Wv, bv, Qb, Kb, Vb);
    }
    hipLaunchKernelGGL(temporal_attn_4715, dim3(1024), dim3(256), 0, stream, Qb, Kb, Vb, outp);
    hipLaunchKernelGGL(others_attn_4715, dim3(256), dim3(256), 0, stream, Qb, Kb, Vb, outp);
}